// Round 3
// baseline (2236.349 us; speedup 1.0000x reference)
//
#include <hip/hip_runtime.h>
#include <stdint.h>

#define NBATCH 16
#define HW_ (1 << 20)            // 1024*1024 per batch
#define TPB 256

#define NBPB_H 128               // blocks per batch for hist pass
#define EPB_H (HW_ / NBPB_H)     // 8192 elements per block
#define ITER_H (EPB_H / (TPB * 4)) // 8 float4 per thread

#define NBPB_F 256               // blocks per batch for main pass
#define FCHUNK (HW_ / NBPB_F)    // 4096 elements per block

#define CAND_CAP 32768           // ambiguous candidates per batch (bin1 count <= ~22K)
#define TIE_CAP 4096

typedef float f4v __attribute__((ext_vector_type(4)));

struct BParams {
    unsigned int k;        // n_train
    unsigned int bin1top;  // selected coarse bin as raw top16 value (sentinel 0x7FFFFFFF if k==0)
    unsigned int r;        // rank remaining within bin1 (k - count_above)
    unsigned int mode;     // 0 = no train, 1 = normal
};

__device__ __forceinline__ unsigned int score_bits(float p, int m) {
    bool correct = (p > 0.5f) == (m == 1);
    float conf = fmaxf(p, 1.0f - p);
    float base = correct ? ((conf > 0.85f) ? 1.0f : 2.0f)
                         : ((conf > 0.85f) ? 4.0f : 3.0f);
    float bonus = (conf - 0.5f) * 0.5f;   // exact in f32
    float s = correct ? (base - bonus) : (base + bonus);
    return __float_as_uint(s);            // positive floats: bit order == value order
}

// Pass 1: 512-bin coarse histogram on (score_bits >> 16) - 0x3F40, 8 LDS sub-hists.
__global__ void k_hist1(const float4* __restrict__ pred4, const int4* __restrict__ mask4,
                        unsigned int* __restrict__ hist1, unsigned int* __restrict__ nannot) {
    __shared__ unsigned int lh[512 * 8];
    __shared__ unsigned int lann;
    int b = blockIdx.x / NBPB_H;
    int blk = blockIdx.x % NBPB_H;
    for (int i = threadIdx.x; i < 512 * 8; i += TPB) lh[i] = 0;
    if (threadIdx.x == 0) lann = 0;
    __syncthreads();
    int sub = threadIdx.x & 7;
    unsigned int myann = 0;
    int l4base = blk * (EPB_H / 4);
    for (int j = 0; j < ITER_H; j++) {
        int i4l = l4base + j * TPB + threadIdx.x;
        size_t g4 = (size_t)b * (HW_ / 4) + i4l;
        float4 p = pred4[g4];
        int4 m = mask4[g4];
        float pa[4] = {p.x, p.y, p.z, p.w};
        int ma[4] = {m.x, m.y, m.z, m.w};
#pragma unroll
        for (int l = 0; l < 4; l++) {
            if (ma[l] != 2) {
                myann++;
                unsigned int sb = score_bits(pa[l], ma[l]);
                int bin = (int)(sb >> 16) - 0x3F40;
                bin = min(max(bin, 0), 511);
                atomicAdd(&lh[bin * 8 + sub], 1u);
            }
        }
    }
    atomicAdd(&lann, myann);
    __syncthreads();
    for (int i = threadIdx.x; i < 512; i += TPB) {
        unsigned int s = 0;
#pragma unroll
        for (int q = 0; q < 8; q++) s += lh[i * 8 + q];
        if (s) atomicAdd(&hist1[b * 512 + i], s);
    }
    if (threadIdx.x == 0) atomicAdd(&nannot[b], lann);
}

// Find coarse bin containing the k-th largest (LDS suffix scan over 512 bins).
__global__ void k_find1(const unsigned int* __restrict__ hist1,
                        const unsigned int* __restrict__ nannot, BParams* prm) {
    int b = blockIdx.x;
    int t = threadIdx.x;
    __shared__ unsigned int sfx[513];
    __shared__ unsigned int sk;
    sfx[t] = hist1[b * 512 + t];
    sfx[t + 256] = hist1[b * 512 + t + 256];
    if (t == 0) {
        sfx[512] = 0;
        unsigned int n = nannot[b];
        sk = (unsigned int)(int)((float)n * 0.5f);  // matches astype(f32)*0.5 -> int32
    }
    __syncthreads();
    for (int off = 1; off < 512; off <<= 1) {
        unsigned int a0 = (t + off < 512) ? sfx[t + off] : 0u;
        unsigned int a1 = (t + 256 + off < 512) ? sfx[t + 256 + off] : 0u;
        __syncthreads();
        sfx[t] += a0;
        sfx[t + 256] += a1;
        __syncthreads();
    }
    unsigned int k = sk;
    if (k == 0) {
        if (t == 0) {
            BParams P;
            P.k = 0; P.bin1top = 0x7FFFFFFFu; P.r = 0; P.mode = 0;
            prm[b] = P;
        }
        return;
    }
#pragma unroll
    for (int h = 0; h < 2; h++) {
        int i = t + h * 256;
        if (sfx[i] >= k && sfx[i + 1] < k) {
            BParams P;
            P.k = k;
            P.bin1top = (unsigned int)i + 0x3F40u;
            P.r = k - sfx[i + 1];
            P.mode = 1;
            prm[b] = P;
        }
    }
}

// Main fused pass: provisional masks (LDS-staged aligned stores), BCE for definite-train,
// wave-aggregated collection of ambiguous (coarse == bin1) candidates.
__global__ void k_main(const float4* __restrict__ pred4, const int4* __restrict__ mask4,
                       const BParams* __restrict__ prm, float* __restrict__ out,
                       float* __restrict__ partials, unsigned int* __restrict__ cand_cnt,
                       unsigned int* __restrict__ cand_idx, unsigned int* __restrict__ cand_sb,
                       float* __restrict__ cand_bce) {
    int b = blockIdx.x / NBPB_F;
    int blk = blockIdx.x % NBPB_F;
    BParams P = prm[b];
    unsigned int target = P.bin1top;
    __shared__ float ltr[FCHUNK];
    __shared__ float lho[FCHUNK];
    __shared__ float red[TPB];
    float acc = 0.0f;
    int ibase = blk * FCHUNK;
    unsigned int lane = threadIdx.x & 63u;
    unsigned long long below = (lane == 0) ? 0ull : ((1ull << lane) - 1ull);
    for (int j = 0; j < FCHUNK / (TPB * 4); j++) {   // 4 iterations
        int li4 = j * TPB + threadIdx.x;             // local float4 idx [0,1024)
        size_t g4 = (size_t)b * (HW_ / 4) + (ibase / 4) + li4;
        float4 p = pred4[g4];
        int4 m = mask4[g4];
        float pa[4] = {p.x, p.y, p.z, p.w};
        int ma[4] = {m.x, m.y, m.z, m.w};
#pragma unroll
        for (int l = 0; l < 4; l++) {
            bool ann = (ma[l] != 2);
            unsigned int sb = score_bits(pa[l], ma[l]);
            unsigned int coarse = sb >> 16;
            bool tr = ann && (coarse > target);
            bool amb = ann && (coarse == target);
            ltr[li4 * 4 + l] = tr ? 1.0f : 0.0f;
            lho[li4 * 4 + l] = (ann && !tr) ? 1.0f : 0.0f;  // ambiguous provisional holdout
            float bce = 0.0f;
            if (tr || amb) {
                float pc = fminf(fmaxf(pa[l], 1e-7f), 1.0f - 1e-7f);
                bce = (ma[l] == 1) ? -__logf(pc) : -__logf(1.0f - pc);
            }
            if (tr) acc += bce;
            // wave-aggregated candidate push
            unsigned long long mk = __ballot(amb);
            if (mk) {
                unsigned int my = (unsigned int)__popcll(mk & below);
                unsigned int cnt = (unsigned int)__popcll(mk);
                int leader = __ffsll(mk) - 1;
                unsigned int basep = 0;
                if ((int)lane == leader) basep = atomicAdd(&cand_cnt[b], cnt);
                basep = __shfl(basep, leader, 64);
                if (amb) {
                    unsigned int pos = basep + my;
                    if (pos < CAND_CAP) {
                        size_t o = (size_t)b * CAND_CAP + pos;
                        cand_idx[o] = (unsigned int)(ibase + li4 * 4 + l);
                        cand_sb[o] = sb;
                        cand_bce[o] = bce;
                    }
                }
            }
        }
    }
    __syncthreads();
    // out layout: out[0]=loss, train at out[1 .. 1+16M), holdout next.
    float* trout = out + 1;
    float* hoout = out + 1 + (size_t)NBATCH * HW_;
    size_t Gbase = (size_t)b * HW_ + (size_t)ibase;
    for (int v = threadIdx.x; v < FCHUNK / 4 - 1; v += TPB) {
        int e = 3 + 4 * v;
        f4v tv = { ltr[e], ltr[e + 1], ltr[e + 2], ltr[e + 3] };
        f4v hv = { lho[e], lho[e + 1], lho[e + 2], lho[e + 3] };
        __builtin_nontemporal_store(tv, (f4v*)(trout + Gbase + e));
        __builtin_nontemporal_store(hv, (f4v*)(hoout + Gbase + e));
    }
    if (threadIdx.x < 3) {
        trout[Gbase + threadIdx.x] = ltr[threadIdx.x];
        hoout[Gbase + threadIdx.x] = lho[threadIdx.x];
    }
    if (threadIdx.x == 3) {
        trout[Gbase + FCHUNK - 1] = ltr[FCHUNK - 1];
        hoout[Gbase + FCHUNK - 1] = lho[FCHUNK - 1];
    }
    red[threadIdx.x] = acc;
    __syncthreads();
    for (int off = TPB / 2; off > 0; off >>= 1) {
        if (threadIdx.x < off) red[threadIdx.x] += red[threadIdx.x + off];
        __syncthreads();
    }
    if (threadIdx.x == 0) partials[blockIdx.x] = red[0];
}

// Fixup: exact select within candidates (two-level LDS hist + tie rank), scatter-correct
// masks, accumulate tie BCE. One block per batch.
__global__ void k_fixup(const unsigned int* __restrict__ cand_cnt,
                        const unsigned int* __restrict__ cand_idx,
                        const unsigned int* __restrict__ cand_sb,
                        const float* __restrict__ cand_bce,
                        const BParams* __restrict__ prm, float* __restrict__ out,
                        float* __restrict__ tie_partials) {
    int b = blockIdx.x;
    int t = threadIdx.x;
    __shared__ unsigned int h[4096];
    __shared__ unsigned int sfx[257];
    __shared__ unsigned int tie_idx[TIE_CAP];
    __shared__ unsigned int misc[8];  // [0]=c4 [1]=r4 [2]=sstar [3]=T [4]=allTies [5]=tieCnt [6]=idxcut
    __shared__ float red[TPB];
    BParams P = prm[b];
    if (P.mode == 0) {
        if (t == 0) tie_partials[b] = 0.0f;
        return;
    }
    unsigned int C = cand_cnt[b];
    if (C > CAND_CAP) C = CAND_CAP;
    const unsigned int* ci = cand_idx + (size_t)b * CAND_CAP;
    const unsigned int* cs = cand_sb + (size_t)b * CAND_CAP;
    const float* cb = cand_bce + (size_t)b * CAND_CAP;
    for (int i = t; i < 4096; i += TPB) h[i] = 0;
    if (t < 8) misc[t] = (t == 6) ? 0xFFFFFFFFu : 0u;
    __syncthreads();
    // level 1: 4096-bin hist over (low16 >> 4)
    for (unsigned int i = t; i < C; i += TPB)
        atomicAdd(&h[(cs[i] & 0xFFFFu) >> 4], 1u);
    __syncthreads();
    // group sums (256 groups of 16) + suffix scan
    {
        unsigned int gs = 0;
#pragma unroll
        for (int j = 0; j < 16; j++) gs += h[t * 16 + j];
        sfx[t] = gs;
        if (t == 0) sfx[256] = 0;
    }
    __syncthreads();
    for (int off = 1; off < 256; off <<= 1) {
        unsigned int a = (t + off < 256) ? sfx[t + off] : 0u;
        __syncthreads();
        sfx[t] += a;
        __syncthreads();
    }
    if (sfx[t] >= P.r && sfx[t + 1] < P.r) {
        unsigned int cum = sfx[t + 1];
        for (int j = 15; j >= 0; j--) {
            unsigned int bin = (unsigned int)t * 16 + j;
            if (cum + h[bin] >= P.r) { misc[0] = bin; misc[1] = P.r - cum; break; }
            cum += h[bin];
        }
    }
    __syncthreads();
    unsigned int c4 = misc[0], r4 = misc[1];
    // level 2: exact low-4 hist within sub-bin c4
    if (t < 16) h[t] = 0;
    __syncthreads();
    for (unsigned int i = t; i < C; i += TPB) {
        unsigned int s = cs[i];
        if (((s & 0xFFFFu) >> 4) == c4) atomicAdd(&h[s & 15u], 1u);
    }
    __syncthreads();
    if (t == 0) {
        unsigned int cum = 0;
        for (int v = 15; v >= 0; v--) {
            if (cum + h[v] >= r4) {
                unsigned int T = r4 - cum, E = h[v];
                misc[2] = (P.bin1top << 16) | (c4 << 4) | (unsigned int)v;
                misc[3] = T;
                misc[4] = (T == E) ? 1u : 0u;
                break;
            }
            cum += h[v];
        }
    }
    __syncthreads();
    unsigned int sstar = misc[2], T = misc[3];
    bool allTies = (misc[4] != 0);
    unsigned int idxcut;
    if (allTies) {
        idxcut = 0xFFFFFFFFu;
    } else {
        for (unsigned int i = t; i < C; i += TPB) {
            if (cs[i] == sstar) {
                unsigned int p = atomicAdd(&misc[5], 1u);
                if (p < TIE_CAP) tie_idx[p] = ci[i];
            }
        }
        __syncthreads();
        unsigned int E2 = misc[5];
        if (E2 > TIE_CAP) E2 = TIE_CAP;
        for (unsigned int i = t; i < E2; i += TPB) {
            unsigned int vi = tie_idx[i];
            unsigned int cnt = 0;
            for (unsigned int j = 0; j < E2; j++) cnt += (tie_idx[j] < vi) ? 1u : 0u;
            if (cnt == T - 1) misc[6] = vi;  // T-th smallest tie index
        }
        __syncthreads();
        idxcut = misc[6];
    }
    // scatter-correct masks + tie BCE
    float acc = 0.0f;
    float* trout = out + 1;
    float* hoout = out + 1 + (size_t)NBATCH * HW_;
    size_t base = (size_t)b * HW_;
    for (unsigned int i = t; i < C; i += TPB) {
        unsigned int s = cs[i];
        bool tr = (s > sstar) || (s == sstar && ci[i] <= idxcut);
        if (tr) {
            trout[base + ci[i]] = 1.0f;
            hoout[base + ci[i]] = 0.0f;
            acc += cb[i];
        }
    }
    red[t] = acc;
    __syncthreads();
    for (int off = TPB / 2; off > 0; off >>= 1) {
        if (t < off) red[t] += red[t + off];
        __syncthreads();
    }
    if (t == 0) tie_partials[b] = red[0];
}

__global__ void k_loss(const float* __restrict__ partials, const float* __restrict__ tie_partials,
                       const BParams* __restrict__ prm, float* __restrict__ out) {
    __shared__ double red[TPB];
    double s = 0.0;
    for (int i = threadIdx.x; i < NBATCH * NBPB_F; i += TPB) s += (double)partials[i];
    if (threadIdx.x < NBATCH) s += (double)tie_partials[threadIdx.x];
    red[threadIdx.x] = s;
    __syncthreads();
    for (int off = TPB / 2; off > 0; off >>= 1) {
        if (threadIdx.x < off) red[threadIdx.x] += red[threadIdx.x + off];
        __syncthreads();
    }
    if (threadIdx.x == 0) {
        unsigned long long den = 0;
        for (int b = 0; b < NBATCH; b++) den += prm[b].k;
        float denf = (float)den + 1e-7f;
        out[0] = (float)red[0] / denf;
    }
}

extern "C" void kernel_launch(void* const* d_in, const int* in_sizes, int n_in,
                              void* d_out, int out_size, void* d_ws, size_t ws_size,
                              hipStream_t stream) {
    const float4* pred4 = (const float4*)d_in[0];
    const int4* mask4 = (const int4*)d_in[1];
    float* out = (float*)d_out;

    // workspace layout (u32 words); zeroed region first
    unsigned int* hist1 = (unsigned int*)d_ws;                 // 16*512
    unsigned int* nannot = hist1 + NBATCH * 512;               // 16
    unsigned int* cand_cnt = nannot + NBATCH;                  // 16
    BParams* prm = (BParams*)(cand_cnt + NBATCH);              // 16 structs (16 words... 16*4)
    float* partials = (float*)(prm + NBATCH);                  // 16*256
    float* tie_partials = partials + NBATCH * NBPB_F;          // 16
    unsigned int* cand_idx = (unsigned int*)(tie_partials + NBATCH);  // 16*32768
    unsigned int* cand_sb = cand_idx + NBATCH * CAND_CAP;
    float* cand_bce = (float*)(cand_sb + NBATCH * CAND_CAP);

    size_t zero_bytes = (size_t)(NBATCH * 512 + NBATCH + NBATCH) * 4;  // hist1+nannot+cand_cnt
    hipMemsetAsync(d_ws, 0, zero_bytes, stream);

    dim3 tpb(TPB);
    k_hist1<<<dim3(NBATCH * NBPB_H), tpb, 0, stream>>>(pred4, mask4, hist1, nannot);
    k_find1<<<dim3(NBATCH), tpb, 0, stream>>>(hist1, nannot, prm);
    k_main<<<dim3(NBATCH * NBPB_F), tpb, 0, stream>>>(pred4, mask4, prm, out, partials,
                                                      cand_cnt, cand_idx, cand_sb, cand_bce);
    k_fixup<<<dim3(NBATCH), tpb, 0, stream>>>(cand_cnt, cand_idx, cand_sb, cand_bce,
                                              prm, out, tie_partials);
    k_loss<<<dim3(1), tpb, 0, stream>>>(partials, tie_partials, prm, out);
}

// Round 4
// 404.500 us; speedup vs baseline: 5.5287x; 5.5287x over previous
//
#include <hip/hip_runtime.h>
#include <stdint.h>

#define NBATCH 16
#define HW_ (1 << 20)            // 1024*1024 per batch
#define TPB 256

#define NBPB_H 128               // blocks per batch for hist pass
#define EPB_H (HW_ / NBPB_H)     // 8192 elements per block
#define ITER_H (EPB_H / (TPB * 4)) // 8 float4 per thread

#define NBPB_F 256               // blocks per batch for main pass
#define FCHUNK (HW_ / NBPB_F)    // 4096 elements per block

#define CAND_CAP 32768           // ambiguous candidates per batch (bin1 count <= ~22K)
#define LCAP 512                 // per-block LDS candidate capacity (expected ~60)
#define TIE_CAP 4096
#define CNT_STRIDE 64            // u32 stride between per-batch counters (256 B, no false share)

typedef float f4v __attribute__((ext_vector_type(4)));

struct BParams {
    unsigned int k;        // n_train
    unsigned int bin1top;  // selected coarse bin as raw top16 value (sentinel 0x7FFFFFFF if k==0)
    unsigned int r;        // rank remaining within bin1 (k - count_above)
    unsigned int mode;     // 0 = no train, 1 = normal
};

__device__ __forceinline__ unsigned int score_bits(float p, int m) {
    bool correct = (p > 0.5f) == (m == 1);
    float conf = fmaxf(p, 1.0f - p);
    float base = correct ? ((conf > 0.85f) ? 1.0f : 2.0f)
                         : ((conf > 0.85f) ? 4.0f : 3.0f);
    float bonus = (conf - 0.5f) * 0.5f;   // exact in f32
    float s = correct ? (base - bonus) : (base + bonus);
    return __float_as_uint(s);            // positive floats: bit order == value order
}

// Pass 1: 512-bin coarse histogram on (score_bits >> 16) - 0x3F40, 8 LDS sub-hists.
__global__ void k_hist1(const float4* __restrict__ pred4, const int4* __restrict__ mask4,
                        unsigned int* __restrict__ hist1, unsigned int* __restrict__ nannot) {
    __shared__ unsigned int lh[512 * 8];
    __shared__ unsigned int lann;
    int b = blockIdx.x / NBPB_H;
    int blk = blockIdx.x % NBPB_H;
    for (int i = threadIdx.x; i < 512 * 8; i += TPB) lh[i] = 0;
    if (threadIdx.x == 0) lann = 0;
    __syncthreads();
    int sub = threadIdx.x & 7;
    unsigned int myann = 0;
    int l4base = blk * (EPB_H / 4);
    for (int j = 0; j < ITER_H; j++) {
        int i4l = l4base + j * TPB + threadIdx.x;
        size_t g4 = (size_t)b * (HW_ / 4) + i4l;
        float4 p = pred4[g4];
        int4 m = mask4[g4];
        float pa[4] = {p.x, p.y, p.z, p.w};
        int ma[4] = {m.x, m.y, m.z, m.w};
#pragma unroll
        for (int l = 0; l < 4; l++) {
            if (ma[l] != 2) {
                myann++;
                unsigned int sb = score_bits(pa[l], ma[l]);
                int bin = (int)(sb >> 16) - 0x3F40;
                bin = min(max(bin, 0), 511);
                atomicAdd(&lh[bin * 8 + sub], 1u);
            }
        }
    }
    atomicAdd(&lann, myann);
    __syncthreads();
    for (int i = threadIdx.x; i < 512; i += TPB) {
        unsigned int s = 0;
#pragma unroll
        for (int q = 0; q < 8; q++) s += lh[i * 8 + q];
        if (s) atomicAdd(&hist1[b * 512 + i], s);
    }
    if (threadIdx.x == 0) atomicAdd(&nannot[b], lann);
}

// Find coarse bin containing the k-th largest (LDS suffix scan over 512 bins).
__global__ void k_find1(const unsigned int* __restrict__ hist1,
                        const unsigned int* __restrict__ nannot, BParams* prm) {
    int b = blockIdx.x;
    int t = threadIdx.x;
    __shared__ unsigned int sfx[513];
    __shared__ unsigned int sk;
    sfx[t] = hist1[b * 512 + t];
    sfx[t + 256] = hist1[b * 512 + t + 256];
    if (t == 0) {
        sfx[512] = 0;
        unsigned int n = nannot[b];
        sk = (unsigned int)(int)((float)n * 0.5f);  // matches astype(f32)*0.5 -> int32
    }
    __syncthreads();
    for (int off = 1; off < 512; off <<= 1) {
        unsigned int a0 = (t + off < 512) ? sfx[t + off] : 0u;
        unsigned int a1 = (t + 256 + off < 512) ? sfx[t + 256 + off] : 0u;
        __syncthreads();
        sfx[t] += a0;
        sfx[t + 256] += a1;
        __syncthreads();
    }
    unsigned int k = sk;
    if (k == 0) {
        if (t == 0) {
            BParams P;
            P.k = 0; P.bin1top = 0x7FFFFFFFu; P.r = 0; P.mode = 0;
            prm[b] = P;
        }
        return;
    }
#pragma unroll
    for (int h = 0; h < 2; h++) {
        int i = t + h * 256;
        if (sfx[i] >= k && sfx[i + 1] < k) {
            BParams P;
            P.k = k;
            P.bin1top = (unsigned int)i + 0x3F40u;
            P.r = k - sfx[i + 1];
            P.mode = 1;
            prm[b] = P;
        }
    }
}

// Main fused pass: provisional masks (LDS-staged aligned stores), BCE for definite-train,
// per-block LDS candidate staging with ONE global atomic per block.
__global__ void k_main(const float4* __restrict__ pred4, const int4* __restrict__ mask4,
                       const BParams* __restrict__ prm, float* __restrict__ out,
                       float* __restrict__ partials, unsigned int* __restrict__ cand_cnt,
                       unsigned int* __restrict__ cand_idx, unsigned int* __restrict__ cand_sb,
                       float* __restrict__ cand_bce) {
    int b = blockIdx.x / NBPB_F;
    int blk = blockIdx.x % NBPB_F;
    BParams P = prm[b];
    unsigned int target = P.bin1top;
    __shared__ float ltr[FCHUNK];
    __shared__ float lho[FCHUNK];
    __shared__ float red[TPB];
    __shared__ unsigned int l_idx[LCAP];
    __shared__ unsigned int l_sb[LCAP];
    __shared__ float l_bce[LCAP];
    __shared__ unsigned int lcnt;
    __shared__ unsigned int gbase;
    if (threadIdx.x == 0) lcnt = 0;
    __syncthreads();
    float acc = 0.0f;
    int ibase = blk * FCHUNK;
    for (int j = 0; j < FCHUNK / (TPB * 4); j++) {   // 4 iterations
        int li4 = j * TPB + threadIdx.x;             // local float4 idx [0,1024)
        size_t g4 = (size_t)b * (HW_ / 4) + (ibase / 4) + li4;
        float4 p = pred4[g4];
        int4 m = mask4[g4];
        float pa[4] = {p.x, p.y, p.z, p.w};
        int ma[4] = {m.x, m.y, m.z, m.w};
#pragma unroll
        for (int l = 0; l < 4; l++) {
            bool ann = (ma[l] != 2);
            unsigned int sb = score_bits(pa[l], ma[l]);
            unsigned int coarse = sb >> 16;
            bool tr = ann && (coarse > target);
            bool amb = ann && (coarse == target);
            ltr[li4 * 4 + l] = tr ? 1.0f : 0.0f;
            lho[li4 * 4 + l] = (ann && !tr) ? 1.0f : 0.0f;  // ambiguous provisional holdout
            float bce = 0.0f;
            if (tr || amb) {
                float pc = fminf(fmaxf(pa[l], 1e-7f), 1.0f - 1e-7f);
                bce = (ma[l] == 1) ? -__logf(pc) : -__logf(1.0f - pc);
            }
            if (tr) acc += bce;
            if (amb) {
                unsigned int p0 = atomicAdd(&lcnt, 1u);  // LDS atomic: cheap
                if (p0 < LCAP) {
                    l_idx[p0] = (unsigned int)(ibase + li4 * 4 + l);
                    l_sb[p0] = sb;
                    l_bce[p0] = bce;
                } else {
                    // rare overflow: direct global push (unique slot via same counter)
                    unsigned int gp = atomicAdd(&cand_cnt[b * CNT_STRIDE], 1u);
                    if (gp < CAND_CAP) {
                        size_t o = (size_t)b * CAND_CAP + gp;
                        cand_idx[o] = (unsigned int)(ibase + li4 * 4 + l);
                        cand_sb[o] = sb;
                        cand_bce[o] = bce;
                    }
                }
            }
        }
    }
    __syncthreads();
    // one global reservation per block, then coalesced copy of the LDS list
    unsigned int n = min(lcnt, (unsigned int)LCAP);
    if (threadIdx.x == 0 && n > 0)
        gbase = atomicAdd(&cand_cnt[b * CNT_STRIDE], n);
    __syncthreads();
    for (unsigned int i = threadIdx.x; i < n; i += TPB) {
        unsigned int pos = gbase + i;
        if (pos < CAND_CAP) {
            size_t o = (size_t)b * CAND_CAP + pos;
            cand_idx[o] = l_idx[i];
            cand_sb[o] = l_sb[i];
            cand_bce[o] = l_bce[i];
        }
    }
    // out layout: out[0]=loss, train at out[1 .. 1+16M), holdout next.
    float* trout = out + 1;
    float* hoout = out + 1 + (size_t)NBATCH * HW_;
    size_t Gbase = (size_t)b * HW_ + (size_t)ibase;
    for (int v = threadIdx.x; v < FCHUNK / 4 - 1; v += TPB) {
        int e = 3 + 4 * v;
        f4v tv = { ltr[e], ltr[e + 1], ltr[e + 2], ltr[e + 3] };
        f4v hv = { lho[e], lho[e + 1], lho[e + 2], lho[e + 3] };
        __builtin_nontemporal_store(tv, (f4v*)(trout + Gbase + e));
        __builtin_nontemporal_store(hv, (f4v*)(hoout + Gbase + e));
    }
    if (threadIdx.x < 3) {
        trout[Gbase + threadIdx.x] = ltr[threadIdx.x];
        hoout[Gbase + threadIdx.x] = lho[threadIdx.x];
    }
    if (threadIdx.x == 3) {
        trout[Gbase + FCHUNK - 1] = ltr[FCHUNK - 1];
        hoout[Gbase + FCHUNK - 1] = lho[FCHUNK - 1];
    }
    red[threadIdx.x] = acc;
    __syncthreads();
    for (int off = TPB / 2; off > 0; off >>= 1) {
        if (threadIdx.x < off) red[threadIdx.x] += red[threadIdx.x + off];
        __syncthreads();
    }
    if (threadIdx.x == 0) partials[blockIdx.x] = red[0];
}

// Fixup: exact select within candidates (two-level LDS hist + tie rank), scatter-correct
// masks, accumulate tie BCE. One block per batch.
__global__ void k_fixup(const unsigned int* __restrict__ cand_cnt,
                        const unsigned int* __restrict__ cand_idx,
                        const unsigned int* __restrict__ cand_sb,
                        const float* __restrict__ cand_bce,
                        const BParams* __restrict__ prm, float* __restrict__ out,
                        float* __restrict__ tie_partials) {
    int b = blockIdx.x;
    int t = threadIdx.x;
    __shared__ unsigned int h[4096];
    __shared__ unsigned int sfx[257];
    __shared__ unsigned int tie_idx[TIE_CAP];
    __shared__ unsigned int misc[8];  // [0]=c4 [1]=r4 [2]=sstar [3]=T [4]=allTies [5]=tieCnt [6]=idxcut
    __shared__ float red[TPB];
    BParams P = prm[b];
    if (P.mode == 0) {
        if (t == 0) tie_partials[b] = 0.0f;
        return;
    }
    unsigned int C = cand_cnt[b * CNT_STRIDE];
    if (C > CAND_CAP) C = CAND_CAP;
    const unsigned int* ci = cand_idx + (size_t)b * CAND_CAP;
    const unsigned int* cs = cand_sb + (size_t)b * CAND_CAP;
    const float* cb = cand_bce + (size_t)b * CAND_CAP;
    for (int i = t; i < 4096; i += TPB) h[i] = 0;
    if (t < 8) misc[t] = (t == 6) ? 0xFFFFFFFFu : 0u;
    __syncthreads();
    // level 1: 4096-bin hist over (low16 >> 4)
    for (unsigned int i = t; i < C; i += TPB)
        atomicAdd(&h[(cs[i] & 0xFFFFu) >> 4], 1u);
    __syncthreads();
    // group sums (256 groups of 16) + suffix scan
    {
        unsigned int gs = 0;
#pragma unroll
        for (int j = 0; j < 16; j++) gs += h[t * 16 + j];
        sfx[t] = gs;
        if (t == 0) sfx[256] = 0;
    }
    __syncthreads();
    for (int off = 1; off < 256; off <<= 1) {
        unsigned int a = (t + off < 256) ? sfx[t + off] : 0u;
        __syncthreads();
        sfx[t] += a;
        __syncthreads();
    }
    if (sfx[t] >= P.r && sfx[t + 1] < P.r) {
        unsigned int cum = sfx[t + 1];
        for (int j = 15; j >= 0; j--) {
            unsigned int bin = (unsigned int)t * 16 + j;
            if (cum + h[bin] >= P.r) { misc[0] = bin; misc[1] = P.r - cum; break; }
            cum += h[bin];
        }
    }
    __syncthreads();
    unsigned int c4 = misc[0], r4 = misc[1];
    // level 2: exact low-4 hist within sub-bin c4
    if (t < 16) h[t] = 0;
    __syncthreads();
    for (unsigned int i = t; i < C; i += TPB) {
        unsigned int s = cs[i];
        if (((s & 0xFFFFu) >> 4) == c4) atomicAdd(&h[s & 15u], 1u);
    }
    __syncthreads();
    if (t == 0) {
        unsigned int cum = 0;
        for (int v = 15; v >= 0; v--) {
            if (cum + h[v] >= r4) {
                unsigned int T = r4 - cum, E = h[v];
                misc[2] = (P.bin1top << 16) | (c4 << 4) | (unsigned int)v;
                misc[3] = T;
                misc[4] = (T == E) ? 1u : 0u;
                break;
            }
            cum += h[v];
        }
    }
    __syncthreads();
    unsigned int sstar = misc[2], T = misc[3];
    bool allTies = (misc[4] != 0);
    unsigned int idxcut;
    if (allTies) {
        idxcut = 0xFFFFFFFFu;
    } else {
        for (unsigned int i = t; i < C; i += TPB) {
            if (cs[i] == sstar) {
                unsigned int p = atomicAdd(&misc[5], 1u);
                if (p < TIE_CAP) tie_idx[p] = ci[i];
            }
        }
        __syncthreads();
        unsigned int E2 = misc[5];
        if (E2 > TIE_CAP) E2 = TIE_CAP;
        for (unsigned int i = t; i < E2; i += TPB) {
            unsigned int vi = tie_idx[i];
            unsigned int cnt = 0;
            for (unsigned int j = 0; j < E2; j++) cnt += (tie_idx[j] < vi) ? 1u : 0u;
            if (cnt == T - 1) misc[6] = vi;  // T-th smallest tie index
        }
        __syncthreads();
        idxcut = misc[6];
    }
    // scatter-correct masks + tie BCE
    float acc = 0.0f;
    float* trout = out + 1;
    float* hoout = out + 1 + (size_t)NBATCH * HW_;
    size_t base = (size_t)b * HW_;
    for (unsigned int i = t; i < C; i += TPB) {
        unsigned int s = cs[i];
        bool tr = (s > sstar) || (s == sstar && ci[i] <= idxcut);
        if (tr) {
            trout[base + ci[i]] = 1.0f;
            hoout[base + ci[i]] = 0.0f;
            acc += cb[i];
        }
    }
    red[t] = acc;
    __syncthreads();
    for (int off = TPB / 2; off > 0; off >>= 1) {
        if (t < off) red[t] += red[t + off];
        __syncthreads();
    }
    if (t == 0) tie_partials[b] = red[0];
}

__global__ void k_loss(const float* __restrict__ partials, const float* __restrict__ tie_partials,
                       const BParams* __restrict__ prm, float* __restrict__ out) {
    __shared__ double red[TPB];
    double s = 0.0;
    for (int i = threadIdx.x; i < NBATCH * NBPB_F; i += TPB) s += (double)partials[i];
    if (threadIdx.x < NBATCH) s += (double)tie_partials[threadIdx.x];
    red[threadIdx.x] = s;
    __syncthreads();
    for (int off = TPB / 2; off > 0; off >>= 1) {
        if (threadIdx.x < off) red[threadIdx.x] += red[threadIdx.x + off];
        __syncthreads();
    }
    if (threadIdx.x == 0) {
        unsigned long long den = 0;
        for (int b = 0; b < NBATCH; b++) den += prm[b].k;
        float denf = (float)den + 1e-7f;
        out[0] = (float)red[0] / denf;
    }
}

extern "C" void kernel_launch(void* const* d_in, const int* in_sizes, int n_in,
                              void* d_out, int out_size, void* d_ws, size_t ws_size,
                              hipStream_t stream) {
    const float4* pred4 = (const float4*)d_in[0];
    const int4* mask4 = (const int4*)d_in[1];
    float* out = (float*)d_out;

    // workspace layout (u32 words); zeroed region first: hist1 | cand_cnt(padded) | nannot
    unsigned int* hist1 = (unsigned int*)d_ws;                  // 16*512
    unsigned int* cand_cnt = hist1 + NBATCH * 512;              // 16*CNT_STRIDE (padded)
    unsigned int* nannot = cand_cnt + NBATCH * CNT_STRIDE;      // 16
    BParams* prm = (BParams*)(nannot + NBATCH);                 // 16 structs
    float* partials = (float*)(prm + NBATCH);                   // 16*256
    float* tie_partials = partials + NBATCH * NBPB_F;           // 16
    unsigned int* cand_idx = (unsigned int*)(tie_partials + NBATCH);  // 16*32768
    unsigned int* cand_sb = cand_idx + NBATCH * CAND_CAP;
    float* cand_bce = (float*)(cand_sb + NBATCH * CAND_CAP);

    size_t zero_bytes = (size_t)(NBATCH * 512 + NBATCH * CNT_STRIDE + NBATCH) * 4;
    hipMemsetAsync(d_ws, 0, zero_bytes, stream);

    dim3 tpb(TPB);
    k_hist1<<<dim3(NBATCH * NBPB_H), tpb, 0, stream>>>(pred4, mask4, hist1, nannot);
    k_find1<<<dim3(NBATCH), tpb, 0, stream>>>(hist1, nannot, prm);
    k_main<<<dim3(NBATCH * NBPB_F), tpb, 0, stream>>>(pred4, mask4, prm, out, partials,
                                                      cand_cnt, cand_idx, cand_sb, cand_bce);
    k_fixup<<<dim3(NBATCH), tpb, 0, stream>>>(cand_cnt, cand_idx, cand_sb, cand_bce,
                                              prm, out, tie_partials);
    k_loss<<<dim3(1), tpb, 0, stream>>>(partials, tie_partials, prm, out);
}

// Round 5
// 284.170 us; speedup vs baseline: 7.8698x; 1.4234x over previous
//
#include <hip/hip_runtime.h>
#include <stdint.h>

#define NBATCH 16
#define HW_ (1 << 20)            // 1024*1024 per batch
#define TPB 256

#define NBPB_H 32                // blocks per batch for hist pass
#define TPB_H 512
#define EPB_H (HW_ / NBPB_H)     // 32768 elements per block
#define ITER_H (EPB_H / (TPB_H * 4)) // 16 float4 per thread

#define NBINS 8192               // fine bins on score_bits >> 12; base 0x3F400
#define FBASE 0x3F400

#define NBPB_F 256               // blocks per batch for main pass
#define FCHUNK (HW_ / NBPB_F)    // 4096 elements per block

#define CAND_CAP 32768           // ambiguous candidates per batch (fine-bin count ~350)
#define LCAP 512                 // per-block LDS candidate capacity
#define TIE_CAP 4096
#define CNT_STRIDE 64            // u32 stride between per-batch counters (256 B)

typedef float f4v __attribute__((ext_vector_type(4)));

struct BParams {
    unsigned int k;        // n_train
    unsigned int bin1f;    // selected fine bin as raw (score_bits>>12) value; 0xFFFFFFFF if k==0
    unsigned int r;        // rank remaining within bin1f (k - count_above)
    unsigned int mode;     // 0 = no train, 1 = normal
};

__device__ __forceinline__ unsigned int score_bits(float p, int m) {
    bool correct = (p > 0.5f) == (m == 1);
    float conf = fmaxf(p, 1.0f - p);
    float base = correct ? ((conf > 0.85f) ? 1.0f : 2.0f)
                         : ((conf > 0.85f) ? 4.0f : 3.0f);
    float bonus = (conf - 0.5f) * 0.5f;   // exact in f32
    float s = correct ? (base - bonus) : (base + bonus);
    return __float_as_uint(s);            // positive floats: bit order == value order
}

// Pass 1: 8192-bin fine histogram on (score_bits>>12) - FBASE. Single LDS hist.
__global__ void k_hist1(const float4* __restrict__ pred4, const int4* __restrict__ mask4,
                        unsigned int* __restrict__ hist1) {
    __shared__ unsigned int lh[NBINS];
    int b = blockIdx.x / NBPB_H;
    int blk = blockIdx.x % NBPB_H;
    for (int i = threadIdx.x; i < NBINS; i += TPB_H) lh[i] = 0;
    __syncthreads();
    int l4base = blk * (EPB_H / 4);
    for (int j = 0; j < ITER_H; j++) {
        int i4l = l4base + j * TPB_H + threadIdx.x;
        size_t g4 = (size_t)b * (HW_ / 4) + i4l;
        float4 p = pred4[g4];
        int4 m = mask4[g4];
        float pa[4] = {p.x, p.y, p.z, p.w};
        int ma[4] = {m.x, m.y, m.z, m.w};
#pragma unroll
        for (int l = 0; l < 4; l++) {
            if (ma[l] != 2) {
                unsigned int sb = score_bits(pa[l], ma[l]);
                int fb = (int)(sb >> 12) - FBASE;
                fb = min(max(fb, 0), NBINS - 1);
                atomicAdd(&lh[fb], 1u);
            }
        }
    }
    __syncthreads();
    for (int i = threadIdx.x; i < NBINS; i += TPB_H)
        if (lh[i]) atomicAdd(&hist1[b * NBINS + i], lh[i]);
}

// Find fine bin containing the k-th largest; k derived from hist total.
__global__ void k_find1(const unsigned int* __restrict__ hist1, BParams* prm) {
    int b = blockIdx.x;
    int t = threadIdx.x;
    __shared__ unsigned int cs_[257];
    const unsigned int* h = hist1 + (size_t)b * NBINS;
    // chunk sums: thread t sums bins [32t, 32t+32) with uint4 loads
    {
        const uint4* h4 = (const uint4*)(h + t * 32);
        unsigned int s = 0;
#pragma unroll
        for (int j = 0; j < 8; j++) { uint4 v = h4[j]; s += v.x + v.y + v.z + v.w; }
        cs_[t] = s;
        if (t == 0) cs_[256] = 0;
    }
    __syncthreads();
    for (int off = 1; off < 256; off <<= 1) {
        unsigned int a = (t + off < 256) ? cs_[t + off] : 0u;
        __syncthreads();
        cs_[t] += a;
        __syncthreads();
    }
    unsigned int n = cs_[0];                       // total annotated
    unsigned int k = (unsigned int)(int)((float)n * 0.5f);  // astype(f32)*0.5 -> int32
    if (k == 0) {
        if (t == 0) {
            BParams P;
            P.k = 0; P.bin1f = 0xFFFFFFFFu; P.r = 0; P.mode = 0;
            prm[b] = P;
        }
        return;
    }
    if (cs_[t] >= k && cs_[t + 1] < k) {           // unique boundary chunk
        unsigned int cum = cs_[t + 1];
        for (int j = 31; j >= 0; j--) {
            unsigned int hb = h[t * 32 + j];
            if (cum + hb >= k) {
                BParams P;
                P.k = k;
                P.bin1f = (unsigned int)(FBASE + t * 32 + j);
                P.r = k - cum;
                P.mode = 1;
                prm[b] = P;
                break;
            }
            cum += hb;
        }
    }
}

// Main fused pass: byte-code mask staging (stride-1 LDS, no conflicts), BCE for
// definite-train, per-block LDS candidate staging, one global atomic per block.
__global__ void k_main(const float4* __restrict__ pred4, const int4* __restrict__ mask4,
                       const BParams* __restrict__ prm, float* __restrict__ out,
                       float* __restrict__ partials, unsigned int* __restrict__ cand_cnt,
                       unsigned int* __restrict__ cand_idx, unsigned int* __restrict__ cand_sb,
                       float* __restrict__ cand_bce) {
    int b = blockIdx.x / NBPB_F;
    int blk = blockIdx.x % NBPB_F;
    BParams P = prm[b];
    unsigned int target = P.bin1f;
    __shared__ unsigned int lcode[FCHUNK / 4];   // 2-bit code per elem, 4 per u32
    __shared__ float red[TPB];
    __shared__ unsigned int l_idx[LCAP];
    __shared__ unsigned int l_sb[LCAP];
    __shared__ float l_bce[LCAP];
    __shared__ unsigned int lcnt;
    __shared__ unsigned int gbase;
    if (threadIdx.x == 0) lcnt = 0;
    __syncthreads();
    float acc = 0.0f;
    int ibase = blk * FCHUNK;
    for (int j = 0; j < FCHUNK / (TPB * 4); j++) {   // 4 iterations
        int v = j * TPB + threadIdx.x;               // word index [0,1024)
        size_t g4 = (size_t)b * (HW_ / 4) + (ibase / 4) + v;
        float4 p = pred4[g4];
        int4 m = mask4[g4];
        float pa[4] = {p.x, p.y, p.z, p.w};
        int ma[4] = {m.x, m.y, m.z, m.w};
        unsigned int cw = 0;
#pragma unroll
        for (int l = 0; l < 4; l++) {
            bool ann = (ma[l] != 2);
            unsigned int sb = score_bits(pa[l], ma[l]);
            unsigned int fine = sb >> 12;
            bool tr = ann && (fine > target);
            bool amb = ann && (fine == target);
            unsigned int code = (tr ? 1u : 0u) | ((ann && !tr) ? 2u : 0u);
            cw |= code << (8 * l);
            float bce = 0.0f;
            if (tr || amb) {
                float pc = fminf(fmaxf(pa[l], 1e-7f), 1.0f - 1e-7f);
                bce = (ma[l] == 1) ? -__logf(pc) : -__logf(1.0f - pc);
            }
            if (tr) acc += bce;
            if (amb) {
                unsigned int p0 = atomicAdd(&lcnt, 1u);  // LDS atomic
                if (p0 < LCAP) {
                    l_idx[p0] = (unsigned int)(ibase + v * 4 + l);
                    l_sb[p0] = sb;
                    l_bce[p0] = bce;
                } else {
                    unsigned int gp = atomicAdd(&cand_cnt[b * CNT_STRIDE], 1u);
                    if (gp < CAND_CAP) {
                        size_t o = (size_t)b * CAND_CAP + gp;
                        cand_idx[o] = (unsigned int)(ibase + v * 4 + l);
                        cand_sb[o] = sb;
                        cand_bce[o] = bce;
                    }
                }
            }
        }
        lcode[v] = cw;   // stride-1 ds_write_b32, conflict-free
    }
    __syncthreads();
    // one global reservation per block, coalesced copy of LDS candidate list
    unsigned int n = min(lcnt, (unsigned int)LCAP);
    if (threadIdx.x == 0 && n > 0)
        gbase = atomicAdd(&cand_cnt[b * CNT_STRIDE], n);
    __syncthreads();
    for (unsigned int i = threadIdx.x; i < n; i += TPB) {
        unsigned int pos = gbase + i;
        if (pos < CAND_CAP) {
            size_t o = (size_t)b * CAND_CAP + pos;
            cand_idx[o] = l_idx[i];
            cand_sb[o] = l_sb[i];
            cand_bce[o] = l_bce[i];
        }
    }
    // out layout: out[0]=loss, train at out[1 .. 1+16M), holdout next.
    float* trout = out + 1;
    float* hoout = out + 1 + (size_t)NBATCH * HW_;
    size_t Gbase = (size_t)b * HW_ + (size_t)ibase;
    // aligned float4 stores covering local elems [3, 4095): out-f4 v' covers
    // elems 3+4v'..6+4v' = byte 3 of word v' and bytes 0..2 of word v'+1.
    for (int v = threadIdx.x; v < FCHUNK / 4 - 1; v += TPB) {
        unsigned int w0 = lcode[v];
        unsigned int w1 = lcode[v + 1];
        unsigned int c0 = (w0 >> 24) & 0xFFu;
        unsigned int c1 = w1 & 0xFFu;
        unsigned int c2 = (w1 >> 8) & 0xFFu;
        unsigned int c3 = (w1 >> 16) & 0xFFu;
        int e = 3 + 4 * v;
        f4v tv = { (float)(c0 & 1u), (float)(c1 & 1u), (float)(c2 & 1u), (float)(c3 & 1u) };
        f4v hv = { (float)((c0 >> 1) & 1u), (float)((c1 >> 1) & 1u),
                   (float)((c2 >> 1) & 1u), (float)((c3 >> 1) & 1u) };
        __builtin_nontemporal_store(tv, (f4v*)(trout + Gbase + e));
        __builtin_nontemporal_store(hv, (f4v*)(hoout + Gbase + e));
    }
    if (threadIdx.x < 3) {   // head elems 0,1,2
        unsigned int c = (lcode[0] >> (8 * threadIdx.x)) & 0xFFu;
        trout[Gbase + threadIdx.x] = (float)(c & 1u);
        hoout[Gbase + threadIdx.x] = (float)((c >> 1) & 1u);
    }
    if (threadIdx.x == 3) {  // tail elem 4095
        unsigned int c = (lcode[FCHUNK / 4 - 1] >> 24) & 0xFFu;
        trout[Gbase + FCHUNK - 1] = (float)(c & 1u);
        hoout[Gbase + FCHUNK - 1] = (float)((c >> 1) & 1u);
    }
    red[threadIdx.x] = acc;
    __syncthreads();
    for (int off = TPB / 2; off > 0; off >>= 1) {
        if (threadIdx.x < off) red[threadIdx.x] += red[threadIdx.x + off];
        __syncthreads();
    }
    if (threadIdx.x == 0) partials[blockIdx.x] = red[0];
}

// Fixup: exact low-12-bit select within candidates, tie-break on index, scatter-correct
// masks, accumulate tie BCE. One block per batch; C ~ a few hundred.
__global__ void k_fixup(const unsigned int* __restrict__ cand_cnt,
                        const unsigned int* __restrict__ cand_idx,
                        const unsigned int* __restrict__ cand_sb,
                        const float* __restrict__ cand_bce,
                        const BParams* __restrict__ prm, float* __restrict__ out,
                        float* __restrict__ tie_partials) {
    int b = blockIdx.x;
    int t = threadIdx.x;
    __shared__ unsigned int h[4096];
    __shared__ unsigned int cs_[257];
    __shared__ unsigned int tie_idx[TIE_CAP];
    __shared__ unsigned int misc[8];  // [0]=v* [1]=T [2]=allTies [3]=tieCnt [4]=idxcut
    __shared__ float red[TPB];
    BParams P = prm[b];
    if (P.mode == 0) {
        if (t == 0) tie_partials[b] = 0.0f;
        return;
    }
    unsigned int C = cand_cnt[b * CNT_STRIDE];
    if (C > CAND_CAP) C = CAND_CAP;
    const unsigned int* ci = cand_idx + (size_t)b * CAND_CAP;
    const unsigned int* cs = cand_sb + (size_t)b * CAND_CAP;
    const float* cb = cand_bce + (size_t)b * CAND_CAP;
    for (int i = t; i < 4096; i += TPB) h[i] = 0;
    if (t < 8) misc[t] = (t == 4) ? 0xFFFFFFFFu : 0u;
    __syncthreads();
    // exact 4096-bin hist on low-12 bits
    for (unsigned int i = t; i < C; i += TPB)
        atomicAdd(&h[cs[i] & 0xFFFu], 1u);
    __syncthreads();
    // chunk sums of 16 + suffix scan
    {
        unsigned int gs = 0;
#pragma unroll
        for (int j = 0; j < 16; j++) gs += h[t * 16 + j];
        cs_[t] = gs;
        if (t == 0) cs_[256] = 0;
    }
    __syncthreads();
    for (int off = 1; off < 256; off <<= 1) {
        unsigned int a = (t + off < 256) ? cs_[t + off] : 0u;
        __syncthreads();
        cs_[t] += a;
        __syncthreads();
    }
    if (cs_[t] >= P.r && cs_[t + 1] < P.r) {
        unsigned int cum = cs_[t + 1];
        for (int j = 15; j >= 0; j--) {
            unsigned int hb = h[t * 16 + j];
            if (cum + hb >= P.r) {
                unsigned int T = P.r - cum;
                misc[0] = (unsigned int)(t * 16 + j);
                misc[1] = T;
                misc[2] = (T == hb) ? 1u : 0u;
                break;
            }
            cum += hb;
        }
    }
    __syncthreads();
    unsigned int vstar = misc[0], T = misc[1];
    bool allTies = (misc[2] != 0);
    unsigned int idxcut;
    if (allTies) {
        idxcut = 0xFFFFFFFFu;
    } else {
        for (unsigned int i = t; i < C; i += TPB) {
            if ((cs[i] & 0xFFFu) == vstar) {
                unsigned int p = atomicAdd(&misc[3], 1u);
                if (p < TIE_CAP) tie_idx[p] = ci[i];
            }
        }
        __syncthreads();
        unsigned int E2 = misc[3];
        if (E2 > TIE_CAP) E2 = TIE_CAP;
        for (unsigned int i = t; i < E2; i += TPB) {
            unsigned int vi = tie_idx[i];
            unsigned int cnt = 0;
            for (unsigned int j = 0; j < E2; j++) cnt += (tie_idx[j] < vi) ? 1u : 0u;
            if (cnt == T - 1) misc[4] = vi;  // T-th smallest tie index
        }
        __syncthreads();
        idxcut = misc[4];
    }
    // scatter-correct masks + tie BCE
    float acc = 0.0f;
    float* trout = out + 1;
    float* hoout = out + 1 + (size_t)NBATCH * HW_;
    size_t base = (size_t)b * HW_;
    for (unsigned int i = t; i < C; i += TPB) {
        unsigned int low = cs[i] & 0xFFFu;
        bool tr = (low > vstar) || (low == vstar && ci[i] <= idxcut);
        if (tr) {
            trout[base + ci[i]] = 1.0f;
            hoout[base + ci[i]] = 0.0f;
            acc += cb[i];
        }
    }
    red[t] = acc;
    __syncthreads();
    for (int off = TPB / 2; off > 0; off >>= 1) {
        if (t < off) red[t] += red[t + off];
        __syncthreads();
    }
    if (t == 0) tie_partials[b] = red[0];
}

__global__ void k_loss(const float* __restrict__ partials, const float* __restrict__ tie_partials,
                       const BParams* __restrict__ prm, float* __restrict__ out) {
    __shared__ double red[TPB];
    double s = 0.0;
    for (int i = threadIdx.x; i < NBATCH * NBPB_F; i += TPB) s += (double)partials[i];
    if (threadIdx.x < NBATCH) s += (double)tie_partials[threadIdx.x];
    red[threadIdx.x] = s;
    __syncthreads();
    for (int off = TPB / 2; off > 0; off >>= 1) {
        if (threadIdx.x < off) red[threadIdx.x] += red[threadIdx.x + off];
        __syncthreads();
    }
    if (threadIdx.x == 0) {
        unsigned long long den = 0;
        for (int b = 0; b < NBATCH; b++) den += prm[b].k;
        float denf = (float)den + 1e-7f;
        out[0] = (float)red[0] / denf;
    }
}

extern "C" void kernel_launch(void* const* d_in, const int* in_sizes, int n_in,
                              void* d_out, int out_size, void* d_ws, size_t ws_size,
                              hipStream_t stream) {
    const float4* pred4 = (const float4*)d_in[0];
    const int4* mask4 = (const int4*)d_in[1];
    float* out = (float*)d_out;

    // workspace layout (u32 words); zeroed region first: hist1 | cand_cnt(padded)
    unsigned int* hist1 = (unsigned int*)d_ws;                  // 16*8192
    unsigned int* cand_cnt = hist1 + NBATCH * NBINS;            // 16*CNT_STRIDE
    BParams* prm = (BParams*)(cand_cnt + NBATCH * CNT_STRIDE);  // 16 structs
    float* partials = (float*)(prm + NBATCH);                   // 16*256
    float* tie_partials = partials + NBATCH * NBPB_F;           // 16
    unsigned int* cand_idx = (unsigned int*)(tie_partials + NBATCH);  // 16*32768
    unsigned int* cand_sb = cand_idx + NBATCH * CAND_CAP;
    float* cand_bce = (float*)(cand_sb + NBATCH * CAND_CAP);

    size_t zero_bytes = (size_t)(NBATCH * NBINS + NBATCH * CNT_STRIDE) * 4;
    hipMemsetAsync(d_ws, 0, zero_bytes, stream);

    k_hist1<<<dim3(NBATCH * NBPB_H), dim3(TPB_H), 0, stream>>>(pred4, mask4, hist1);
    k_find1<<<dim3(NBATCH), dim3(TPB), 0, stream>>>(hist1, prm);
    k_main<<<dim3(NBATCH * NBPB_F), dim3(TPB), 0, stream>>>(pred4, mask4, prm, out, partials,
                                                            cand_cnt, cand_idx, cand_sb, cand_bce);
    k_fixup<<<dim3(NBATCH), dim3(TPB), 0, stream>>>(cand_cnt, cand_idx, cand_sb, cand_bce,
                                                    prm, out, tie_partials);
    k_loss<<<dim3(1), dim3(TPB), 0, stream>>>(partials, tie_partials, prm, out);
}